// Round 1
// baseline (708.683 us; speedup 1.0000x reference)
//
#include <hip/hip_runtime.h>
#include <hip/hip_bf16.h>

#define MT 32768      // tokens total (64*512)
#define KD 2048       // B*C = 32*64
#define DD 256        // embedding dim
#define NB 32         // codebooks
#define NC 64         // codewords
#define MTILE 16      // tokens per workgroup

typedef short s8v __attribute__((ext_vector_type(8)));   // 8 x bf16 (as short), 4 VGPRs
typedef float f4v __attribute__((ext_vector_type(4)));   // MFMA accumulator
typedef unsigned short u16;

__device__ __forceinline__ u16 f2bf(float x) {
  // round-to-nearest-even f32 -> bf16 (inputs are finite, no NaN handling needed)
  unsigned int u = __float_as_uint(x);
  u += 0x7FFFu + ((u >> 16) & 1u);
  return (u16)(u >> 16);
}

// codebook (32,64,256) fp32  ->  Bt (256,2048) bf16, Bt[n][k] = cb[k][n], k = b*64+c
__global__ void transpose_cb(const float* __restrict__ cb, u16* __restrict__ Bt) {
  __shared__ u16 tile[64][65];
  const int k0 = blockIdx.x * 64;
  const int n0 = blockIdx.y * 64;
  const int t = threadIdx.x;
#pragma unroll
  for (int i = 0; i < 16; ++i) {
    int idx = i * 256 + t;       // 0..4095 over a 64(k) x 64(n) tile
    int kl = idx >> 6, nl = idx & 63;
    tile[kl][nl] = f2bf(cb[(size_t)(k0 + kl) * DD + n0 + nl]);  // coalesced read
  }
  __syncthreads();
  int nl = t >> 2, ch = t & 3;   // thread -> output row n0+nl, 16-wide k chunk
  u16 tmp[16];
#pragma unroll
  for (int i = 0; i < 16; ++i) tmp[i] = tile[ch * 16 + i][nl];
  u16* dst = Bt + (size_t)(n0 + nl) * KD + k0 + ch * 16;
#pragma unroll
  for (int i = 0; i < 16; ++i) dst[i] = tmp[i];
}

// Fused gather + softmax(axis=b) + GEMM.
// Block: 256 threads (4 waves), MTILE=16 tokens, full D=256 (wave w -> cols [64w,64w+64)).
// LDS: A-tile 16 x 2048 bf16 = 64 KB exactly -> 2 blocks/CU.
// Swizzle: element (m,k) stored at m*2048 + ((k>>3) ^ (m&7))*8 + (k&7)  (16B-group XOR)
__global__ __launch_bounds__(256, 2) void fused_emb(
    const int* __restrict__ tokens, const float* __restrict__ code,
    const u16* __restrict__ Bt, float* __restrict__ out) {
  __shared__ __align__(16) u16 W[MTILE * KD];

  const int t = threadIdx.x;
  const int wave = t >> 6, lane = t & 63;
  const int tok_base = blockIdx.x * MTILE;

  // ---- Phase 1: gather + softmax over b (32 values per (m,c)), write bf16 weights to LDS
  // wave handles tokens [4*wave, 4*wave+4); lane = codeword c
#pragma unroll 1
  for (int i = 0; i < 4; ++i) {
    const int m = wave * 4 + i;
    const int tok = tokens[tok_base + m];
    const float* row = code + (size_t)tok * KD;
    const int c = lane;
    float g[NB];
#pragma unroll
    for (int b = 0; b < NB; ++b) g[b] = row[b * NC + c];   // 32 coalesced 256B loads
    float mx = g[0];
#pragma unroll
    for (int b = 1; b < NB; ++b) mx = fmaxf(mx, g[b]);
    float s = 0.f;
#pragma unroll
    for (int b = 0; b < NB; ++b) {
      g[b] = exp2f((g[b] - mx) * 1.44269504f);
      s += g[b];
    }
    const float inv = 1.0f / s;
    const int sw = m & 7;
    u16* wrow = W + m * KD;
#pragma unroll
    for (int b = 0; b < NB; ++b) {
      int k = b * NC + c;
      int grp = (k >> 3) ^ sw;
      wrow[(grp << 3) + (k & 7)] = f2bf(g[b] * inv);
    }
  }
  __syncthreads();

  // ---- Phase 2: GEMM 16 x 2048 x 64 per wave via mfma_f32_16x16x32_bf16
  const int lid = lane & 15, quad = lane >> 4;
  const int nb = wave * 64;
  const u16* btl = Bt + (size_t)(nb + lid) * KD + quad * 8;  // B frag base for this lane
  const u16* Wl = W + lid * KD;
  const int sw = lid & 7;

  f4v acc0 = {0.f, 0.f, 0.f, 0.f};
  f4v acc1 = {0.f, 0.f, 0.f, 0.f};
  f4v acc2 = {0.f, 0.f, 0.f, 0.f};
  f4v acc3 = {0.f, 0.f, 0.f, 0.f};

  auto ldA = [&](int k0) -> s8v {
    int grp = ((k0 >> 3) + quad) ^ sw;
    return *(const s8v*)(Wl + (grp << 3));   // ds_read_b128, swizzled
  };

  s8v a_c = ldA(0);
  s8v b0 = *(const s8v*)(btl + 0 * 16 * KD);
  s8v b1 = *(const s8v*)(btl + 1 * 16 * KD);
  s8v b2 = *(const s8v*)(btl + 2 * 16 * KD);
  s8v b3 = *(const s8v*)(btl + 3 * 16 * KD);

#pragma unroll 2
  for (int s = 0; s < 63; ++s) {
    const int k1 = (s + 1) * 32;
    s8v a_n = ldA(k1);
    s8v c0 = *(const s8v*)(btl + 0 * 16 * KD + k1);
    s8v c1 = *(const s8v*)(btl + 1 * 16 * KD + k1);
    s8v c2 = *(const s8v*)(btl + 2 * 16 * KD + k1);
    s8v c3 = *(const s8v*)(btl + 3 * 16 * KD + k1);
    acc0 = __builtin_amdgcn_mfma_f32_16x16x32_bf16(a_c, b0, acc0, 0, 0, 0);
    acc1 = __builtin_amdgcn_mfma_f32_16x16x32_bf16(a_c, b1, acc1, 0, 0, 0);
    acc2 = __builtin_amdgcn_mfma_f32_16x16x32_bf16(a_c, b2, acc2, 0, 0, 0);
    acc3 = __builtin_amdgcn_mfma_f32_16x16x32_bf16(a_c, b3, acc3, 0, 0, 0);
    a_c = a_n; b0 = c0; b1 = c1; b2 = c2; b3 = c3;
  }
  acc0 = __builtin_amdgcn_mfma_f32_16x16x32_bf16(a_c, b0, acc0, 0, 0, 0);
  acc1 = __builtin_amdgcn_mfma_f32_16x16x32_bf16(a_c, b1, acc1, 0, 0, 0);
  acc2 = __builtin_amdgcn_mfma_f32_16x16x32_bf16(a_c, b2, acc2, 0, 0, 0);
  acc3 = __builtin_amdgcn_mfma_f32_16x16x32_bf16(a_c, b3, acc3, 0, 0, 0);

  // ---- Epilogue: C/D layout col = lane&15, row = quad*4 + reg   [m89/m91]
  float* orow = out + (size_t)tok_base * DD + nb + lid;
#pragma unroll
  for (int r = 0; r < 4; ++r) {
    const int mo = quad * 4 + r;
    float* p = orow + (size_t)mo * DD;
    p[0]  = acc0[r];
    p[16] = acc1[r];
    p[32] = acc2[r];
    p[48] = acc3[r];
  }
}

extern "C" void kernel_launch(void* const* d_in, const int* in_sizes, int n_in,
                              void* d_out, int out_size, void* d_ws, size_t ws_size,
                              hipStream_t stream) {
  const int* tokens = (const int*)d_in[0];
  const float* code = (const float*)d_in[1];
  const float* codebook = (const float*)d_in[2];
  float* out = (float*)d_out;
  u16* Bt = (u16*)d_ws;  // 256*2048*2 = 1 MiB scratch

  transpose_cb<<<dim3(KD / 64, DD / 64), 256, 0, stream>>>(codebook, Bt);
  fused_emb<<<MT / MTILE, 256, 0, stream>>>(tokens, code, Bt, out);
}

// Round 2
// 564.146 us; speedup vs baseline: 1.2562x; 1.2562x over previous
//
#include <hip/hip_runtime.h>
#include <hip/hip_bf16.h>

#define MT 32768      // tokens total (64*512)
#define KD 2048       // B*C = 32*64
#define DD 256        // embedding dim
#define NB 32         // codebooks
#define NC 64         // codewords
#define MTILE 64      // tokens per block
#define KC 512        // K-chunk (8 codebooks)
#define NCH 4         // chunks
#define LOG2E 1.44269504f

typedef short s8v __attribute__((ext_vector_type(8)));   // 8 x bf16 (4 VGPRs)
typedef float f4v __attribute__((ext_vector_type(4)));   // MFMA accumulator
typedef unsigned short u16;

__device__ __forceinline__ u16 f2bf(float x) {
  unsigned int u = __float_as_uint(x);
  u += 0x7FFFu + ((u >> 16) & 1u);
  return (u16)(u >> 16);
}

// codebook (32,64,256) f32 -> Bp in MFMA-fragment order (1 MiB bf16).
// Frag (nt, s, lane), 16 B each, contiguous across lanes:
//   value[j] = B[k = s*32 + (lane>>4)*8 + j][n = nt*16 + (lane&15)]
// where B[k][n] = cb[k*256 + n]. GEMM reads one frag as a single coalesced
// 1 KB global_load_dwordx4 per wave.
__global__ void pack_b(const float* __restrict__ cb, u16* __restrict__ Bp) {
  int idx = blockIdx.x * 256 + threadIdx.x;   // 0..65535
  int lane = idx & 63;
  int s = (idx >> 6) & 63;
  int nt = idx >> 12;                         // 0..15
  int n = nt * 16 + (lane & 15);
  int kb = s * 32 + (lane >> 4) * 8;
  s8v v;
#pragma unroll
  for (int j = 0; j < 8; ++j) v[j] = (short)f2bf(cb[(size_t)(kb + j) * DD + n]);
  *(s8v*)(Bp + (size_t)idx * 8) = v;
}

// Fused gather + softmax(axis=b) + GEMM.
// 512 threads = 8 waves; MTILE=64 tokens/block; grid = 512 -> 2 blocks/CU,
// 4 waves/SIMD. Stats pass keeps per-(token,c) max & 1/sum in registers;
// then 4 K-chunks: rebuild bf16 weights (L2/L3-resident rows) into a 64 KB
// LDS A-chunk, GEMM 16 k-steps against fragment-packed B.
// A swizzle: (m, kl) at m*512 + ((kl>>3) ^ (m&7))*8 + (kl&7).
__global__ __launch_bounds__(512, 4) void fused_emb(
    const int* __restrict__ tokens, const float* __restrict__ code,
    const u16* __restrict__ Bp, float* __restrict__ out) {
  __shared__ __align__(16) u16 A[MTILE * KC];   // 64 KB

  const int t = threadIdx.x;
  const int w = t >> 6, lane = t & 63;
  const int tokb = blockIdx.x * MTILE;
  const int c = lane;                 // codeword index in gather/softmax role
  const int lid = lane & 15, quad = lane >> 4;
  const int mg = w >> 2, ng = w & 3;  // GEMM wave coords: 2 M-groups x 4 N-groups

  // token ids for this wave's 8 build-tokens (wave-uniform)
  int tok[8];
#pragma unroll
  for (int i = 0; i < 8; ++i) tok[i] = tokens[tokb + w * 8 + i];

  // ---- Stats pass: per (token, c) max over b and 1/sum(exp). Full row read (HBM).
  float mx[8], inv[8];
#pragma unroll
  for (int i = 0; i < 8; ++i) {
    const float* row = code + (size_t)tok[i] * KD + c;
    float g[NB];
#pragma unroll
    for (int b = 0; b < NB; ++b) g[b] = row[b * NC];
    float m0 = g[0];
#pragma unroll
    for (int b = 1; b < NB; ++b) m0 = fmaxf(m0, g[b]);
    float s = 0.f;
#pragma unroll
    for (int b = 0; b < NB; ++b) s += exp2f((g[b] - m0) * LOG2E);
    mx[i] = m0;
    inv[i] = 1.0f / s;
  }

  f4v acc[2][4] = {};   // [m-tile][n-tile], 16x16 each

  for (int ch = 0; ch < NCH; ++ch) {
    // ---- Build A-chunk: wave w writes tokens [8w, 8w+8), b in [8ch, 8ch+8).
    // Rows are L2/L3-hot from the stats pass.
#pragma unroll
    for (int i = 0; i < 8; ++i) {
      const int m = w * 8 + i;                    // m & 7 == i
      const float* row = code + (size_t)tok[i] * KD + c;
      u16* arow = A + m * KC;
#pragma unroll
      for (int bl = 0; bl < 8; ++bl) {
        const int b = ch * 8 + bl;
        float wv = exp2f((row[b * NC] - mx[i]) * LOG2E) * inv[i];
        const int kl = bl * 64 + c;
        const int grp = (kl >> 3) ^ i;
        arow[(grp << 3) + (kl & 7)] = f2bf(wv);
      }
    }
    __syncthreads();

    // ---- GEMM this chunk: 16 k-steps of 32, wave tile 32(M) x 64(N)
    auto ldA = [&](int mt, int sl) -> s8v {
      const int m = mg * 32 + mt * 16 + lid;
      const int kl = sl * 32 + quad * 8;
      const int grp = (kl >> 3) ^ (m & 7);
      return *(const s8v*)(A + m * KC + (grp << 3));
    };
    auto ldB = [&](int nt, int sl) -> s8v {
      const int fi = ((ng * 4 + nt) * 64 + ch * 16 + sl) * 64 + lane;
      return *(const s8v*)(Bp + (size_t)fi * 8);
    };

    s8v a0 = ldA(0, 0), a1 = ldA(1, 0);
    s8v bc[4];
#pragma unroll
    for (int nt = 0; nt < 4; ++nt) bc[nt] = ldB(nt, 0);

#pragma unroll 1
    for (int sl = 0; sl < 15; ++sl) {
      s8v a0n = ldA(0, sl + 1), a1n = ldA(1, sl + 1);
      s8v bn[4];
#pragma unroll
      for (int nt = 0; nt < 4; ++nt) bn[nt] = ldB(nt, sl + 1);
#pragma unroll
      for (int nt = 0; nt < 4; ++nt) {
        acc[0][nt] = __builtin_amdgcn_mfma_f32_16x16x32_bf16(a0, bc[nt], acc[0][nt], 0, 0, 0);
        acc[1][nt] = __builtin_amdgcn_mfma_f32_16x16x32_bf16(a1, bc[nt], acc[1][nt], 0, 0, 0);
      }
      a0 = a0n; a1 = a1n;
#pragma unroll
      for (int nt = 0; nt < 4; ++nt) bc[nt] = bn[nt];
    }
#pragma unroll
    for (int nt = 0; nt < 4; ++nt) {
      acc[0][nt] = __builtin_amdgcn_mfma_f32_16x16x32_bf16(a0, bc[nt], acc[0][nt], 0, 0, 0);
      acc[1][nt] = __builtin_amdgcn_mfma_f32_16x16x32_bf16(a1, bc[nt], acc[1][nt], 0, 0, 0);
    }
    __syncthreads();
  }

  // ---- Epilogue: C/D layout col = lane&15, row = quad*4 + reg  [m89/m91]
  float* ob = out + (size_t)(tokb + mg * 32) * DD + ng * 64 + lid;
#pragma unroll
  for (int mt = 0; mt < 2; ++mt)
#pragma unroll
    for (int r = 0; r < 4; ++r) {
      float* p = ob + (size_t)(mt * 16 + quad * 4 + r) * DD;
#pragma unroll
      for (int nt = 0; nt < 4; ++nt) p[nt * 16] = acc[mt][nt][r];
    }
}

extern "C" void kernel_launch(void* const* d_in, const int* in_sizes, int n_in,
                              void* d_out, int out_size, void* d_ws, size_t ws_size,
                              hipStream_t stream) {
  const int* tokens = (const int*)d_in[0];
  const float* code = (const float*)d_in[1];
  const float* codebook = (const float*)d_in[2];
  float* out = (float*)d_out;
  u16* Bp = (u16*)d_ws;   // 1 MiB fragment-packed codebook

  pack_b<<<256, 256, 0, stream>>>(codebook, Bp);
  fused_emb<<<MT / MTILE, 512, 0, stream>>>(tokens, code, Bp, out);
}